// Round 12
// baseline (224.407 us; speedup 1.0000x reference)
//
#include <hip/hip_runtime.h>

#define ROWS_TOTAL 131072
#define XST 224             // g_xb row stride in bf16 elements (448 B, zero-padded)

typedef float f32x4 __attribute__((ext_vector_type(4)));
typedef short s16x8 __attribute__((ext_vector_type(8)));

// W fragment-linear, per 112-col group:
//   ushort idx = ((cg*7 + kk)*112 + col112)*32 + ks*8 + e   (zero-padded k>=196)
__device__ unsigned short g_Wb3[7 * 7 * 112 * 32];          // 351 KB
// x patchified, bf16, row stride 224 ushorts (zero-padded k = 196..223)
__device__ unsigned short g_xb[(size_t)ROWS_TOTAL * XST];   // 58.7 MB

__device__ __forceinline__ unsigned short f2bf(float f) {
    unsigned int u = __builtin_bit_cast(unsigned int, f);
    u += 0x7fffu + ((u >> 16) & 1u);        // round-to-nearest-even
    return (unsigned short)(u >> 16);
}

__global__ void prep_w(const float* __restrict__ W) {
    int t = blockIdx.x * 256 + threadIdx.x;   // 784 cols * 56 k-quads
    if (t >= 784 * 56) return;
    int col = t / 56;
    int k0  = (t - col * 56) * 4;
    uint2 pk;
    if (k0 < 196) {
        f32x4 d = *(const f32x4*)(W + col * 196 + k0);
        pk.x = (unsigned int)f2bf(d[0]) | ((unsigned int)f2bf(d[1]) << 16);
        pk.y = (unsigned int)f2bf(d[2]) | ((unsigned int)f2bf(d[3]) << 16);
    } else {
        pk.x = 0u; pk.y = 0u;
    }
    int cg = col / 112, col112 = col - cg * 112;
    int kk = k0 >> 5, rem = k0 & 31, ks = rem >> 3, e0 = rem & 7;
    size_t di = (size_t)(((cg * 7 + kk) * 112 + col112)) * 32 + ks * 8 + e0;
    *(uint2*)(g_Wb3 + di) = pk;
}

// patchify: x[32768,28,28] fp32 -> g_xb[131072][224] bf16 (zero-padded)
__global__ void prep_x(const float* __restrict__ x) {
    const int NV = ROWS_TOTAL / 4 * 784 / 4;            // 6,422,528 float4s
    const f32x4* xv = (const f32x4*)x;
    for (int v = blockIdx.x * 256 + threadIdx.x; v < NV; v += gridDim.x * 256) {
        f32x4 d = xv[v];
        int F   = v * 4;
        int img = F / 784;
        int rem = F - img * 784;
        int h   = rem / 28;
        int w0  = rem - h * 28;          // in {0,4,...,24}
        int ph  = h / 14;
        int r   = h - ph * 14;
        int rowb = img * 4 + ph * 2;
        #pragma unroll
        for (int p = 0; p < 2; ++p) {
            int w  = w0 + 2 * p;         // even => bf16 pair stays inside one patch
            int pw = (w >= 14) ? 1 : 0;
            int c  = w - pw * 14;
            int row = rowb + pw;
            unsigned int pack = (unsigned int)f2bf(d[2 * p]) |
                                ((unsigned int)f2bf(d[2 * p + 1]) << 16);
            *(unsigned int*)((char*)g_xb + (size_t)row * (XST * 2) + (r * 14 + c) * 2) = pack;
        }
    }
    // zero pad k = 196..223 for every row
    for (int t = blockIdx.x * 256 + threadIdx.x; t < ROWS_TOTAL * 7; t += gridDim.x * 256) {
        int row = t / 7;
        int j   = t - row * 7;
        *(uint2*)((char*)g_xb + (size_t)row * (XST * 2) + 392 + j * 8) = (uint2){0u, 0u};
    }
}

__device__ __forceinline__ void gload_lds16(void* lds, const void* g) {
    __builtin_amdgcn_global_load_lds(
        (const __attribute__((address_space(1))) unsigned int*)g,
        (__attribute__((address_space(3))) unsigned int*)lds, 16, 0, 0);
}

// Block: 64 out rows x ALL 784 cols. 4 waves; wave = 16 rows x 784 cols with the
// FULL row in registers (acc[7][7] f32x4 = 196 VGPR, fully unrolled cg loop).
// sW (49 KiB, one col-group) re-staged 7x. Epilogue: each wave stores 16
// complete rows (50 KB) densely & monotonically -> full-line write-combining.
// LDS 49 KiB -> 2 blocks/CU; block skew overlaps stores with compute.
__global__ __launch_bounds__(256, 2)
void patch_linear_mfma(const float* __restrict__ blin,
                       float* __restrict__ out) {
    __shared__ __align__(16) char sW[49 * 1024];   // [kk][col112][ks][16B]

    const int tid  = threadIdx.x;
    const int l    = tid & 63;
    const int wv   = tid >> 6;          // 0..3
    const int lrow = l & 15;
    const int lk   = l >> 4;

    const int blk = blockIdx.x;         // row group (64 rows), 0..2047

    // ---- stage W group 0: 49 x 1 KiB linear async DMA ----
    const char* wsrc0 = (const char*)g_Wb3 + l * 16;
    #pragma unroll
    for (int c = 0; c < 13; ++c) {
        int ch = wv + c * 4;
        if (ch < 49) gload_lds16(sW + ch * 1024, wsrc0 + ch * 1024);
    }

    // ---- x fragments -> registers (overlaps the DMA) ----
    const char* xbp = (const char*)g_xb +
                      ((size_t)blk * 64 + wv * 16 + lrow) * 448 + lk * 16;
    s16x8 xf[7];
    #pragma unroll
    for (int kk = 0; kk < 7; ++kk)
        xf[kk] = *(const s16x8*)(xbp + kk * 64);

    // ---- acc init = bias (full row in registers) ----
    f32x4 acc[7][7];
    #pragma unroll
    for (int cg = 0; cg < 7; ++cg)
        #pragma unroll
        for (int n = 0; n < 7; ++n)
            acc[cg][n] = *(const f32x4*)(blin + cg * 112 + n * 16 + lk * 4);

    __syncthreads();   // W group 0 + xf ready

    const char* wb = sW + lrow * 64 + lk * 16;

    #pragma unroll
    for (int cg = 0; cg < 7; ++cg) {
        #pragma unroll
        for (int kk = 0; kk < 7; ++kk) {
            #pragma unroll
            for (int n = 0; n < 7; ++n) {
                s16x8 wf = *(const s16x8*)(wb + kk * 7168 + n * 1024);
                acc[cg][n] = __builtin_amdgcn_mfma_f32_16x16x32_bf16(
                    wf, xf[kk], acc[cg][n], 0, 0, 0);
            }
        }
        if (cg < 6) {
            __syncthreads();   // all waves done reading sW[cg]
            const char* ws = (const char*)g_Wb3 + (size_t)(cg + 1) * 50176 + l * 16;
            #pragma unroll
            for (int c = 0; c < 13; ++c) {
                int ch = wv + c * 4;
                if (ch < 49) gload_lds16(sW + ch * 1024, ws + ch * 1024);
            }
            __syncthreads();   // sW[cg+1] ready
        }
    }

    // ---- store: wave writes its 16 rows densely (49 dwordx4/lane, monotonic) ----
    float* orow = out + ((size_t)blk * 64 + wv * 16 + lrow) * 784 + lk * 4;
    #pragma unroll
    for (int cg = 0; cg < 7; ++cg)
        #pragma unroll
        for (int n = 0; n < 7; ++n)
            *(f32x4*)(orow + cg * 112 + n * 16) = acc[cg][n];
}

extern "C" void kernel_launch(void* const* d_in, const int* in_sizes, int n_in,
                              void* d_out, int out_size, void* d_ws, size_t ws_size,
                              hipStream_t stream) {
    const float* x    = (const float*)d_in[0];   // [32768,1,28,28]
    const float* Wlin = (const float*)d_in[1];   // [784,196]
    const float* blin = (const float*)d_in[2];   // [784]
    float* out = (float*)d_out;                  // [32768,4,784]

    prep_w<<<(784 * 56 + 255) / 256, 256, 0, stream>>>(Wlin);
    prep_x<<<4096, 256, 0, stream>>>(x);

    dim3 grid(ROWS_TOTAL / 64);                  // 2048 blocks, dense 200KB regions
    dim3 block(256);
    patch_linear_mfma<<<grid, block, 0, stream>>>(blin, out);
}